// Round 6
// baseline (202.460 us; speedup 1.0000x reference)
//
#include <hip/hip_runtime.h>

// EOQLinear: int4-quantized GEMV.
//   out[n] = sum_b scales[n,b] * sum_{q in block b} w_int[n,q] * x[q]
// packed_w[n,j] is an int32 in [0,256): low nibble -> k=2j, high nibble -> k=2j+1,
// both offset by -8.
//
// DTYPE NOTE (round-1): harness stages the reference's float16 tensors as
// FLOAT32. x, scales, out are f32.
//
// ROUND-6 post-mortem: rounds 4 & 5 crashed (GPU memory fault -> host abort)
// because the scales row BASE used stride (halfK>>sShift)=256 instead of
// blocksPerRow=64 -> reads up to ~6 MiB past the 2 MiB scales array. The
// nontemporal load was innocent. Fixed: base stride = blocksPerRow, passed
// explicitly (as in the known-good round 2).
//
// KEPT (round-3 primary theory, now actually testable): channel-diffusion
// stagger. Round 2 ran at ~680 GB/s effective (197 us) while the harness's own
// 512 MB fills hit 6.9 TB/s; all waves walked their 16 KB rows in lockstep ->
// live addresses all congruent mod 16 KB -> DRAM channel aliasing. Wave for
// row n starts its column walk at chunk (n mod iters) and wraps, spreading
// concurrent traffic across all 1 KB offsets within the 16 KB period.
// Coalescing unchanged (1 KB contiguous per wave-instruction).
//
// Layout: one 64-lane wave per output row, 4 rows per 256-thread block
// (2048 blocks, 8 blocks/CU, zero LDS). x: 32 KB, cache-resident, 2x float4
// per lane-iter. Per-quant-block scale applied once per 4-int chunk
// (4 consecutive packed ints share one 64-int quant block; srow[j4>>4]).

#define WAVES_PER_BLOCK 4

__global__ __launch_bounds__(256, 4)
void eoq_gemv_kernel(const float* __restrict__ x,
                     const int* __restrict__ packed_w,
                     const float* __restrict__ scales,
                     float* __restrict__ out,
                     int N, int halfK, int itMask, int sShift, int blocksPerRow)
{
    const int lane = threadIdx.x & 63;
    const int wave = threadIdx.x >> 6;
    const int row  = blockIdx.x * WAVES_PER_BLOCK + wave;
    if (row >= N) return;

    const int4*   __restrict__ w4p =
        reinterpret_cast<const int4*>(packed_w + (size_t)row * halfK);
    const float4* __restrict__ x4p = reinterpret_cast<const float4*>(x);
    const float*  __restrict__ srow = scales + (size_t)row * (size_t)blocksPerRow;

    const int iters = itMask + 1;     // halfK / 256; 16 for K=8192 (power of 2)
    const int phase = row & itMask;   // per-row start chunk -> channel diffusion

    float acc = 0.f;

    #pragma unroll 4
    for (int t = 0; t < iters; ++t) {
        const int it = (t + phase) & itMask;
        const int j4 = (it << 6) + lane;            // 16B-chunk index in the row
        const int4   w4 = w4p[j4];
        const float4 xa = x4p[2 * j4];              // x[8*j4   .. 8*j4+3]
        const float4 xb = x4p[2 * j4 + 1];          // x[8*j4+4 .. 8*j4+7]
        const float  s  = srow[j4 >> sShift];       // quant-block scale (j4/16)

        const unsigned w0 = (unsigned)w4.x;
        const unsigned w1 = (unsigned)w4.y;
        const unsigned w2 = (unsigned)w4.z;
        const unsigned w3 = (unsigned)w4.w;

        float part = 0.f;
        part = fmaf((float)(int)(w0 & 0xFu) - 8.f, xa.x, part);
        part = fmaf((float)(int)(w0 >> 4)   - 8.f, xa.y, part);
        part = fmaf((float)(int)(w1 & 0xFu) - 8.f, xa.z, part);
        part = fmaf((float)(int)(w1 >> 4)   - 8.f, xa.w, part);
        part = fmaf((float)(int)(w2 & 0xFu) - 8.f, xb.x, part);
        part = fmaf((float)(int)(w2 >> 4)   - 8.f, xb.y, part);
        part = fmaf((float)(int)(w3 & 0xFu) - 8.f, xb.z, part);
        part = fmaf((float)(int)(w3 >> 4)   - 8.f, xb.w, part);
        acc = fmaf(s, part, acc);
    }

    // wave-64 reduction
    #pragma unroll
    for (int off = 32; off > 0; off >>= 1)
        acc += __shfl_down(acc, off, 64);

    if (lane == 0) out[row] = acc;
}

extern "C" void kernel_launch(void* const* d_in, const int* in_sizes, int n_in,
                              void* d_out, int out_size, void* d_ws, size_t ws_size,
                              hipStream_t stream) {
    const float* x      = (const float*)d_in[0];
    const int*   pw     = (const int*)d_in[1];
    const float* scales = (const float*)d_in[2];
    float*       out    = (float*)d_out;

    const int K     = in_sizes[0];         // 8192
    const int halfK = K >> 1;              // 4096
    const int N     = in_sizes[1] / halfK; // 8192
    const int blocksPerRow = in_sizes[2] / N;    // K/QB = 64

    // packed ints per quant block = QB/2 = halfK/blocksPerRow (pow2);
    // sShift: 16B-chunk index -> quant-block index = log2(QB/2) - 2 (QB=128 -> 4)
    const int qhalf = halfK / blocksPerRow;
    int qhalfShift = 0;
    while ((1 << qhalfShift) < qhalf) ++qhalfShift;
    const int sShift = qhalfShift - 2;

    const int iters = halfK >> 8;          // column chunks per row (16, pow2)
    const int itMask = iters - 1;

    dim3 grid((N + WAVES_PER_BLOCK - 1) / WAVES_PER_BLOCK), block(256);
    eoq_gemv_kernel<<<grid, block, 0, stream>>>(x, pw, scales, out,
                                                N, halfK, itMask, sShift, blocksPerRow);
}

// Round 7
// 197.051 us; speedup vs baseline: 1.0274x; 1.0274x over previous
//
#include <hip/hip_runtime.h>

// EOQLinear: int4-quantized GEMV.
//   out[n] = sum_b scales[n,b] * sum_{q in block b} w_int[n,q] * x[q]
// packed_w[n,j] is an int32 in [0,256): low nibble -> k=2j, high nibble -> k=2j+1,
// both offset by -8.
//
// DTYPE NOTE (round-1): harness stages the reference's float16 tensors as
// FLOAT32. x, scales, out are f32.
//
// ROUND-7 post-mortem of round 6: the per-row column stagger was NEUTRAL
// (197.5 -> 202.5 us) -> DRAM-channel-aliasing theory dead, stagger removed.
// Key observation: our kernel never appears in the rocprof top-5 (cutoff
// 77 us) while harness dur_us = 202 us -> the kernel dispatch itself is
// < 77 us; the rest is per-replay harness restore work (128 MiB input d2d +
// 512 MiB poison fills at ~78 us). Kernel effective BW is >= 1.7 TB/s, gap to
// the 21 us / 6.3 TB/s floor is ~3x.
//
// ROUND-7 CHANGE: 4 rows per wave. Per K-iteration a wave loads xa/xb ONCE and
// streams 4 independent 16 B weight loads (4 HBM streams/wave -> 4x MLP, 1/4
// the x/scale/addressing overhead per weight byte). Grid 512 blocks (2/CU,
// 8 waves/CU; in-flight weight bytes/CU ~ 64 KiB >> ~9 KiB Little's-law need).
// Coalescing unchanged: each weight load is 1 KiB contiguous per wave.
//
// Layout: block = 256 threads = 4 waves; wave handles rows base..base+3.
// x: 32 KB, cache-resident, 2x float4 per iter. Per-quant-block scale applied
// once per 4-int chunk (srow[j4>>4]); fp32 accumulation, butterfly reduce.

#define ROWS_PER_WAVE 4

__global__ __launch_bounds__(256, 2)
void eoq_gemv_kernel(const float* __restrict__ x,
                     const int* __restrict__ packed_w,
                     const float* __restrict__ scales,
                     float* __restrict__ out,
                     int N, int halfK, int iters, int sShift, int blocksPerRow)
{
    const int lane = threadIdx.x & 63;
    const int wave = threadIdx.x >> 6;
    const int row0 = (blockIdx.x * 4 + wave) * ROWS_PER_WAVE;
    if (row0 >= N) return;

    const float4* __restrict__ x4p = reinterpret_cast<const float4*>(x);

    // Per-row weight/scale bases (constant-indexed, stays in registers).
    const int4* w4p[ROWS_PER_WAVE];
    const float* srow[ROWS_PER_WAVE];
    #pragma unroll
    for (int r = 0; r < ROWS_PER_WAVE; ++r) {
        w4p[r]  = reinterpret_cast<const int4*>(packed_w + (size_t)(row0 + r) * halfK);
        srow[r] = scales + (size_t)(row0 + r) * blocksPerRow;
    }

    float acc[ROWS_PER_WAVE] = {0.f, 0.f, 0.f, 0.f};

    #pragma unroll 2
    for (int it = 0; it < iters; ++it) {
        const int j4 = (it << 6) + lane;            // 16B-chunk index in the row
        const float4 xa = x4p[2 * j4];              // x[8*j4   .. 8*j4+3]
        const float4 xb = x4p[2 * j4 + 1];          // x[8*j4+4 .. 8*j4+7]
        const int    sIdx = j4 >> sShift;           // quant-block index

        #pragma unroll
        for (int r = 0; r < ROWS_PER_WAVE; ++r) {
            const int4  w4 = w4p[r][j4];
            const float s  = srow[r][sIdx];

            const unsigned w0 = (unsigned)w4.x;
            const unsigned w1 = (unsigned)w4.y;
            const unsigned w2 = (unsigned)w4.z;
            const unsigned w3 = (unsigned)w4.w;

            float part = 0.f;
            part = fmaf((float)(int)(w0 & 0xFu) - 8.f, xa.x, part);
            part = fmaf((float)(int)(w0 >> 4)   - 8.f, xa.y, part);
            part = fmaf((float)(int)(w1 & 0xFu) - 8.f, xa.z, part);
            part = fmaf((float)(int)(w1 >> 4)   - 8.f, xa.w, part);
            part = fmaf((float)(int)(w2 & 0xFu) - 8.f, xb.x, part);
            part = fmaf((float)(int)(w2 >> 4)   - 8.f, xb.y, part);
            part = fmaf((float)(int)(w3 & 0xFu) - 8.f, xb.z, part);
            part = fmaf((float)(int)(w3 >> 4)   - 8.f, xb.w, part);
            acc[r] = fmaf(s, part, acc[r]);
        }
    }

    // wave-64 butterfly reduction per row
    #pragma unroll
    for (int r = 0; r < ROWS_PER_WAVE; ++r) {
        float a = acc[r];
        #pragma unroll
        for (int off = 32; off > 0; off >>= 1)
            a += __shfl_down(a, off, 64);
        if (lane == 0 && row0 + r < N) out[row0 + r] = a;
    }
}

extern "C" void kernel_launch(void* const* d_in, const int* in_sizes, int n_in,
                              void* d_out, int out_size, void* d_ws, size_t ws_size,
                              hipStream_t stream) {
    const float* x      = (const float*)d_in[0];
    const int*   pw     = (const int*)d_in[1];
    const float* scales = (const float*)d_in[2];
    float*       out    = (float*)d_out;

    const int K     = in_sizes[0];         // 8192
    const int halfK = K >> 1;              // 4096
    const int N     = in_sizes[1] / halfK; // 8192
    const int blocksPerRow = in_sizes[2] / N;    // K/QB = 64

    // packed ints per quant block = QB/2 = halfK/blocksPerRow (pow2);
    // sShift: 16B-chunk index -> quant-block index = log2(QB/2) - 2 (QB=128 -> 4)
    const int qhalf = halfK / blocksPerRow;
    int qhalfShift = 0;
    while ((1 << qhalfShift) < qhalf) ++qhalfShift;
    const int sShift = qhalfShift - 2;

    const int iters = halfK >> 8;          // 16B-chunk columns per row / 64 lanes

    const int rowsPerBlock = 4 * ROWS_PER_WAVE;  // 16
    dim3 grid((N + rowsPerBlock - 1) / rowsPerBlock), block(256);
    eoq_gemv_kernel<<<grid, block, 0, stream>>>(x, pw, scales, out,
                                                N, halfK, iters, sShift, blocksPerRow);
}